// Round 8
// baseline (209.069 us; speedup 1.0000x reference)
//
#include <hip/hip_runtime.h>
#include <cstdint>
#include <cstddef>

#define MB_   4096
#define NK_   8
#define DM_   1024
#define DT_   128

typedef __bf16 bf16;
typedef __bf16 bf16x8 __attribute__((ext_vector_type(8)));
typedef __bf16 bf16x4 __attribute__((ext_vector_type(4)));
typedef float  f32x4  __attribute__((ext_vector_type(4)));

__device__ __forceinline__ void gload_lds16(const void* g, void* l) {
  __builtin_amdgcn_global_load_lds(
      (__attribute__((address_space(1))) void*)g,
      (__attribute__((address_space(3))) void*)l,
      16, 0, 0);
}

// chunk swizzle: logical 16B-chunk c of row r lives at LDS chunk c ^ hsw(r).
__device__ __forceinline__ int hsw(int r) { return (r ^ (r >> 2)) & 3; }

// ---------------------------------------------------------------------------
// merged prep: blocks [0,8192): proj_w f32->bf16 (4 elem/thread)
//              blocks [8192,12288): w_vs transpose -> WvT bf16 (1 elem/thread)
__global__ void prep_kernel(const float* __restrict__ pw, bf16* __restrict__ pwb,
                            const float* __restrict__ wvs, bf16* __restrict__ wvt) {
  int b = blockIdx.x;
  if (b < 8192) {
    size_t i = ((size_t)b * 256 + threadIdx.x) * 4;
    float4 f = *(const float4*)&pw[i];
    bf16x4 o = { (bf16)f.x, (bf16)f.y, (bf16)f.z, (bf16)f.w };
    *(bf16x4*)&pwb[i] = o;
  } else {
    int o = (b - 8192) * 256 + threadIdx.x;
    int d = o & 1023;
    int t = (o >> 10) & 127;
    int n = o >> 17;
    wvt[o] = (bf16)wvs[(size_t)n * 131072 + (size_t)d * 128 + t];
  }
}

// ---------------------------------------------------------------------------
// GEMM1: v_s[n] = V_n[4096x1024](f32) @ WvT[n][128x1024]^T -> A2 scatter (bf16)
__global__ __launch_bounds__(256, 2) void gemm1_kernel(
    const float* __restrict__ vflat, const bf16* __restrict__ WvT,
    bf16* __restrict__ A2)
{
  __shared__ __align__(16) bf16 As[64 * 32];
  __shared__ __align__(16) bf16 Bs[128 * 32];
  const int tid  = threadIdx.x;
  const int wave = tid >> 6, lane = tid & 63;
  const int wm = wave >> 1, wn = wave & 1;
  const int n  = blockIdx.y;
  const int b0 = blockIdx.x * 64;

  const int r  = tid >> 2;
  const int hr = hsw(r);
  const int cs = (tid & 3) ^ hr;

  const float* ag = vflat + ((size_t)(n * MB_ + b0 + r)) * 1024 + (tid & 3) * 8;
  bf16* awr = As + r * 32 + cs * 8;
  const bf16* bg = WvT + (size_t)n * 131072 + (size_t)r * 1024 + cs * 8;
  char* bsb = (char*)Bs + wave * 1024;

  f32x4 acc[2][4] = {};
  const int krow = lane & 15;
  const int cch  = lane >> 4;
  const int swoff = ((cch ^ hsw(krow)) << 4);

  for (int kt = 0; kt < 32; ++kt) {
    const bf16* bptr = bg + kt * 32;
    gload_lds16(bptr,             bsb);
    gload_lds16(bptr + 64 * 1024, bsb + 4096);
    const float* aptr = ag + kt * 32;
    float4 f0 = *(const float4*)(aptr + 0);
    float4 f1 = *(const float4*)(aptr + 4);
    bf16x8 h0 = { (bf16)f0.x, (bf16)f0.y, (bf16)f0.z, (bf16)f0.w,
                  (bf16)f1.x, (bf16)f1.y, (bf16)f1.z, (bf16)f1.w };
    *(bf16x8*)awr = h0;
    __syncthreads();

    bf16x8 af[2], bfr[4];
    #pragma unroll
    for (int i = 0; i < 2; ++i)
      af[i] = *(const bf16x8*)((const char*)As + (wm * 32 + i * 16 + krow) * 64 + swoff);
    #pragma unroll
    for (int j = 0; j < 4; ++j)
      bfr[j] = *(const bf16x8*)((const char*)Bs + (wn * 64 + j * 16 + krow) * 64 + swoff);
    #pragma unroll
    for (int i = 0; i < 2; ++i)
      #pragma unroll
      for (int j = 0; j < 4; ++j)
        acc[i][j] = __builtin_amdgcn_mfma_f32_16x16x32_bf16(af[i], bfr[j], acc[i][j], 0, 0, 0);
    __syncthreads();
  }

  #pragma unroll
  for (int i = 0; i < 2; ++i) {
    #pragma unroll
    for (int j = 0; j < 4; ++j) {
      int t = wn * 64 + j * 16 + (lane & 15);
      #pragma unroll
      for (int rr = 0; rr < 4; ++rr) {
        int b = b0 + wm * 32 + i * 16 + (lane >> 4) * 4 + rr;
        size_t off = ((size_t)(n * 512 + (b >> 3))) * 1024 + (size_t)(b & 7) * 128 + t;
        A2[off] = (bf16)acc[i][j][rr];
      }
    }
  }
}

// ---------------------------------------------------------------------------
// GEMM2 compiler-scheduled: x[4096][8192] = A2 @ PW^T + pb.
// Tile 256x256, 32 sub-tiles BK=32, 4 LDS buffers, stage 3 ahead,
// ONE barrier per sub-tile; counted vmcnt(8) (T4); interior left to the
// compiler's ds_read<->MFMA interleave (m97-style lgkmcnt(4/3/1/0)).
template<bool ZB>
__global__ __launch_bounds__(512, 2) void gemm2c_kernel(
    const bf16* __restrict__ A2, const bf16* __restrict__ PW,
    const float* __restrict__ pb, void* __restrict__ xoutp)
{
  __shared__ __align__(16) bf16 As[4][8192];  // [buf][256 rows x 32 k] 16KB
  __shared__ __align__(16) bf16 Bs[4][8192];

  const int tid  = threadIdx.x;
  const int w    = tid >> 6;
  const int lane = tid & 63;
  const int wm   = w >> 2;       // 0..1
  const int wn   = w & 3;        // 0..3

  const int bid   = blockIdx.x;          // 0..511
  const int x     = bid & 7;
  const int local = bid >> 3;            // 0..63
  const int mt    = local & 15;
  const int nt    = x * 4 + (local >> 4);
  const int m0    = mt * 256;
  const int n0    = nt * 256;

  // staging: thread tid stages 16B chunk tid of each 128-row half (pre-swizzled src)
  const int rS = tid >> 2;
  const int cS = (tid & 3) ^ hsw(rS);
  const char* aG0 = (const char*)A2 + (size_t)(m0 + rS) * 2048 + cS * 16;
  const char* aG1 = aG0 + (size_t)128 * 2048;
  const char* bG0 = (const char*)PW + (size_t)(n0 + rS) * 2048 + cS * 16;
  const char* bG1 = bG0 + (size_t)128 * 2048;

  #define STAGE(t) { char* dA = (char*)As[(t) & 3] + tid * 16;               \
                     char* dB = (char*)Bs[(t) & 3] + tid * 16;               \
                     gload_lds16(aG0 + (size_t)(t) * 64, dA);                \
                     gload_lds16(aG1 + (size_t)(t) * 64, dA + 8192);         \
                     gload_lds16(bG0 + (size_t)(t) * 64, dB);                \
                     gload_lds16(bG1 + (size_t)(t) * 64, dB + 8192); }

  // prologue: sub-tiles 0,1,2 staged (12 loads); wait tile 0 (8 in flight)
  STAGE(0); STAGE(1); STAGE(2);
  asm volatile("s_waitcnt vmcnt(8)" ::: "memory");
  __builtin_amdgcn_s_barrier();
  __builtin_amdgcn_sched_barrier(0);

  f32x4 acc[8][4] = {};
  const int fr = lane & 15;
  const int g  = lane >> 4;
  const int swoff = ((g ^ hsw(fr)) << 4);
  const int aRd = (wm * 128 + fr) * 64 + swoff;   // byte offset in As[buf]
  const int bRd = (wn * 64  + fr) * 64 + swoff;

  #pragma unroll 1
  for (int s = 0; s < 32; ++s) {
    // issue next stage early (HBM latency hides under this sub-tile's MFMA)
    if (s < 29) STAGE(s + 3);

    const char* pA = (const char*)As[s & 3] + aRd;
    const char* pB = (const char*)Bs[s & 3] + bRd;
    bf16x8 a[8], b[4];
    #pragma unroll
    for (int m = 0; m < 8; ++m) a[m] = *(const bf16x8*)(pA + m * 1024);
    #pragma unroll
    for (int n = 0; n < 4; ++n) b[n] = *(const bf16x8*)(pB + n * 1024);
    #pragma unroll
    for (int m = 0; m < 8; ++m)
      #pragma unroll
      for (int n = 0; n < 4; ++n)
        acc[m][n] = __builtin_amdgcn_mfma_f32_16x16x32_bf16(a[m], b[n], acc[m][n], 0, 0, 0);

    // phase boundary: my reads of buf[s&3] drained; stage(s+1) landed.
    asm volatile("s_waitcnt lgkmcnt(0)" ::: "memory");
    if (s < 29)       { asm volatile("s_waitcnt vmcnt(8)" ::: "memory"); }
    else if (s == 29) { asm volatile("s_waitcnt vmcnt(4)" ::: "memory"); }
    else if (s == 30) { asm volatile("s_waitcnt vmcnt(0)" ::: "memory"); }
    __builtin_amdgcn_s_barrier();
    __builtin_amdgcn_sched_barrier(0);
  }
  #undef STAGE

  // epilogue: x = acc + pb -> bf16 ws (or f32 d_out)
  #pragma unroll
  for (int m = 0; m < 8; ++m) {
    #pragma unroll
    for (int n = 0; n < 4; ++n) {
      int nn = n0 + wn * 64 + n * 16 + fr;
      float pbn = pb[nn];
      #pragma unroll
      for (int r = 0; r < 4; ++r) {
        int mm = m0 + wm * 128 + m * 16 + g * 4 + r;
        size_t off = (size_t)mm * 8192 + nn;
        float val = acc[m][n][r] + pbn;
        if (ZB) ((bf16*)xoutp)[off] = (bf16)val;
        else    ((float*)xoutp)[off] = val;
      }
    }
  }
}

// ---------------------------------------------------------------------------
// LN over 1024-wide rows: x = z + v(residual); ddof=1, eps outside sqrt.
// Also fills the attns output region (all ones) from the first 128 blocks.
template<bool ZB>
__global__ __launch_bounds__(256) void ln_kernel(
    const void* zin, const float* __restrict__ vres,
    const float* __restrict__ gamma, const float* __restrict__ beta,
    float* outp)
{
  __shared__ float red[16];
  const int row = blockIdx.x;
  const int tid = threadIdx.x;
  if (row < 128) outp[(size_t)33554432 + row * 256 + tid] = 1.0f;
  const size_t base = (size_t)row * 1024 + tid * 4;

  float4 rv = *(const float4*)&vres[base];
  float4 x;
  if (ZB) {
    bf16x4 zb4 = *(const bf16x4*)((const bf16*)zin + base);
    x.x = (float)zb4[0] + rv.x; x.y = (float)zb4[1] + rv.y;
    x.z = (float)zb4[2] + rv.z; x.w = (float)zb4[3] + rv.w;
  } else {
    float4 zf = *(const float4*)((const float*)zin + base);
    x.x = zf.x + rv.x; x.y = zf.y + rv.y; x.z = zf.z + rv.z; x.w = zf.w + rv.w;
  }

  float s  = x.x + x.y + x.z + x.w;
  float ss = x.x * x.x + x.y * x.y + x.z * x.z + x.w * x.w;
  #pragma unroll
  for (int m = 32; m >= 1; m >>= 1) {
    s  += __shfl_xor(s,  m, 64);
    ss += __shfl_xor(ss, m, 64);
  }
  const int wave = tid >> 6, lane = tid & 63;
  if (lane == 0) { red[wave] = s; red[wave + 8] = ss; }
  __syncthreads();
  float S  = red[0] + red[1] + red[2] + red[3];
  float SS = red[8] + red[9] + red[10] + red[11];
  float mu  = S * (1.0f / 1024.0f);
  float var = (SS - 1024.0f * mu * mu) * (1.0f / 1023.0f);
  var = var < 0.0f ? 0.0f : var;
  float rs = 1.0f / (sqrtf(var) + 1e-3f);
  float4 gmv = *(const float4*)&gamma[tid * 4];
  float4 be  = *(const float4*)&beta[tid * 4];
  float4 y;
  y.x = (x.x - mu) * rs * gmv.x + be.x;
  y.y = (x.y - mu) * rs * gmv.y + be.y;
  y.z = (x.z - mu) * rs * gmv.z + be.z;
  y.w = (x.w - mu) * rs * gmv.w + be.w;
  *(float4*)&outp[base] = y;
}

// ---------------------------------------------------------------------------
extern "C" void kernel_launch(void* const* d_in, const int* in_sizes, int n_in,
                              void* d_out, int out_size, void* d_ws, size_t ws_size,
                              hipStream_t stream) {
  const float* v     = (const float*)d_in[2];
  const float* wvs   = (const float*)d_in[5];
  const float* pw    = (const float*)d_in[6];
  const float* pb    = (const float*)d_in[7];
  const float* gamma = (const float*)d_in[8];
  const float* beta  = (const float*)d_in[9];
  float* out = (float*)d_out;

  // ws: PW bf16 16M | WvT bf16 2M | A2 bf16 8M | x bf16 64M
  const size_t OFF_WVT = 16777216;
  const size_t OFF_A2  = OFF_WVT + 2097152;
  const size_t OFF_X   = OFF_A2 + 8388608;
  const size_t NEED_ZB = OFF_X + 67108864;

  bf16* PWb = (bf16*)d_ws;
  bf16* WvT = (bf16*)((char*)d_ws + OFF_WVT);
  bf16* A2  = (bf16*)((char*)d_ws + OFF_A2);
  const bool zb = (ws_size >= NEED_ZB);
  void* xbuf = zb ? (void*)((char*)d_ws + OFF_X) : (void*)out;

  hipLaunchKernelGGL(prep_kernel, dim3(12288), dim3(256), 0, stream, pw, PWb, wvs, WvT);
  hipLaunchKernelGGL(gemm1_kernel, dim3(64, 8), dim3(256), 0, stream, v, WvT, A2);
  if (zb) {
    hipLaunchKernelGGL((gemm2c_kernel<true>),  dim3(512), dim3(512), 0, stream, A2, PWb, pb, xbuf);
    hipLaunchKernelGGL((ln_kernel<true>),      dim3(32768), dim3(256), 0, stream, xbuf, v, gamma, beta, out);
  } else {
    hipLaunchKernelGGL((gemm2c_kernel<false>), dim3(512), dim3(512), 0, stream, A2, PWb, pb, xbuf);
    hipLaunchKernelGGL((ln_kernel<false>),     dim3(32768), dim3(256), 0, stream, xbuf, v, gamma, beta, out);
  }
}